// Round 6
// baseline (526.819 us; speedup 1.0000x reference)
//
#include <hip/hip_runtime.h>
#include <cmath>
#include <cstdint>

// Problem constants (from reference)
constexpr int B_ = 8, N_ = 1024, M_ = 512, D_ = 128, S_ = 1536, L_ = 6, DFF_ = 512;
constexpr int ROWS = B_ * S_;   // 12288
constexpr int MAXDEG = 64;      // max attention row degree (actual ~7-25)
constexpr int NBLK = ROWS / 64; // 192 persistent blocks (<= 256 CUs => all resident)

typedef __bf16 bf16x8 __attribute__((ext_vector_type(8)));
typedef float  f32x4  __attribute__((ext_vector_type(4)));
typedef unsigned short u16x8 __attribute__((ext_vector_type(8)));

__device__ inline unsigned short f2bf(float f) {  // RNE fp32 -> bf16
  unsigned u = __float_as_uint(f);
  u += 0x7fffu + ((u >> 16) & 1u);
  return (unsigned short)(u >> 16);
}

// ---------------------------------------------------------------------------
// Adjacency from pcm: allowed(s,k) = (s==k) | Tanner edge. One wave per row.
// exp(-1e9-max) underflows to 0 in fp32 => sparse attention over this list is
// bit-equivalent to the dense masked softmax.
// ---------------------------------------------------------------------------
__global__ void adj_kernel(const int* __restrict__ pcm, int* __restrict__ adj,
                           int* __restrict__ adjcnt) {
  int s = blockIdx.x;
  int lane = threadIdx.x;  // 0..63
  int count = 0;
  for (int base = 0; base < S_; base += 64) {
    int k = base + lane;
    bool allowed;
    if (k == s) allowed = true;
    else if (s < N_ && k >= N_) allowed = pcm[(k - N_) * N_ + s] != 0;
    else if (s >= N_ && k < N_) allowed = pcm[(s - N_) * N_ + k] != 0;
    else allowed = false;
    unsigned long long bal = __ballot(allowed);
    if (allowed) {
      int slot = count + __popcll(bal & ((1ull << lane) - 1ull));
      if (slot < MAXDEG) adj[s * MAXDEG + slot] = k;
    }
    count += __popcll(bal);
  }
  if (lane == 0) adjcnt[s] = count < MAXDEG ? count : MAXDEG;
}

// ---------------------------------------------------------------------------
// x[b,s,d] = table[t[b],d] * src_embed[s,d] * nodes[b,s]; nodes from adjacency.
// Also zeroes the grid-barrier counter (ws is poisoned 0xAA before each call).
// ---------------------------------------------------------------------------
__global__ void xinit_kernel(const float* __restrict__ r_t, const int* __restrict__ adj,
                             const int* __restrict__ adjcnt, const float* __restrict__ se,
                             const int* __restrict__ tt, const float* __restrict__ table,
                             float* __restrict__ x, unsigned* __restrict__ barrier_cnt) {
  int bs = blockIdx.x;
  int b = bs / S_, s = bs % S_;
  int d = threadIdx.x;
  if (bs == 0 && d == 0) *barrier_cnt = 0u;  // kernel boundary flushes before mega
  float node;
  if (s < N_) {
    node = fabsf(r_t[b * N_ + s]);
  } else {
    int cnt = adjcnt[s];
    float sum = 0.f;
    for (int j = 0; j < cnt; ++j) {
      int k = adj[s * MAXDEG + j];
      if (k < N_) {
        float r = r_t[b * N_ + k];
        sum += (r < 0.f) ? 1.f : (r > 0.f ? 0.f : 0.5f);  // bits = 0.5*(1-sign)
      }
    }
    node = fmodf(sum, 2.0f);
  }
  x[(size_t)bs * D_ + d] = table[tt[b] * D_ + d] * se[s * D_ + d] * node;
}

// ---------------------------------------------------------------------------
// Weight convert: fp32 [K][N] -> bf16 transposed [N][K], per layer packed as
//   [3*128][128] (q,k,v) | [128][128] (o) | [512][128] (w1) | [128][512] (w2)
// ---------------------------------------------------------------------------
constexpr int WSEG_QKV = 3 * D_ * D_;            // 49152
constexpr int WSEG_O   = D_ * D_;                // 16384
constexpr int WSEG_1   = D_ * DFF_;              // 65536
constexpr int WSEG_2   = DFF_ * D_;              // 65536
constexpr int WLAYER   = WSEG_QKV + WSEG_O + WSEG_1 + WSEG_2;  // 196608

__global__ void wconv_kernel(const float* __restrict__ Wq, const float* __restrict__ Wk,
                             const float* __restrict__ Wv, const float* __restrict__ Wo,
                             const float* __restrict__ W1, const float* __restrict__ W2,
                             unsigned short* __restrict__ out) {
  int idx = blockIdx.x * blockDim.x + threadIdx.x;
  if (idx >= L_ * WLAYER) return;
  int l = idx / WLAYER, r = idx % WLAYER;
  float v;
  if (r < WSEG_QKV) {
    int which = r / (D_ * D_), i = r % (D_ * D_);
    int n = i / D_, kk = i % D_;
    const float* W = which == 0 ? Wq : (which == 1 ? Wk : Wv);
    v = W[(size_t)l * D_ * D_ + kk * D_ + n];
  } else if (r < WSEG_QKV + WSEG_O) {
    int i = r - WSEG_QKV;
    int n = i / D_, kk = i % D_;
    v = Wo[(size_t)l * D_ * D_ + kk * D_ + n];
  } else if (r < WSEG_QKV + WSEG_O + WSEG_1) {
    int i = r - WSEG_QKV - WSEG_O;
    int n = i / D_, kk = i % D_;          // n in [0,512), kk in [0,128)
    v = W1[(size_t)l * D_ * DFF_ + kk * DFF_ + n];
  } else {
    int i = r - WSEG_QKV - WSEG_O - WSEG_1;
    int n = i / DFF_, kk = i % DFF_;      // n in [0,128), kk in [0,512)
    v = W2[(size_t)l * DFF_ * D_ + kk * D_ + n];
  }
  out[idx] = f2bf(v);
}

// ---------------------------------------------------------------------------
// MFMA helper: wave computes 16 rows x 128 cols (1x8 tiles of 16x16), K=128
// in 4 steps of 32. LDS: 16B chunks XOR-swizzled [row*128 + ((c^(row&15))<<3)].
// ---------------------------------------------------------------------------
__device__ __forceinline__ void mfma16(const unsigned short* As, const unsigned short* Bs,
                                       int rowbase, int quad, int l16, f32x4 (&acc)[8]) {
#pragma unroll
  for (int kk = 0; kk < 4; ++kk) {
    int cb = kk * 4 + quad;
    int row = rowbase + l16;
    bf16x8 a = __builtin_bit_cast(bf16x8, *(const uint4*)&As[row * 128 + ((cb ^ (row & 15)) << 3)]);
    bf16x8 bb[8];
#pragma unroll
    for (int ct = 0; ct < 8; ++ct) {
      int n = ct * 16 + l16;
      bb[ct] = __builtin_bit_cast(bf16x8, *(const uint4*)&Bs[n * 128 + ((cb ^ (n & 15)) << 3)]);
    }
#pragma unroll
    for (int ct = 0; ct < 8; ++ct)
      acc[ct] = __builtin_amdgcn_mfma_f32_16x16x32_bf16(a, bb[ct], acc[ct], 0, 0, 0);
  }
}

// ---------------------------------------------------------------------------
// Device-scope grid barrier (all NBLK blocks hardware-resident by construction:
// 192 blocks x 64 KB LDS on 256 CUs x 160 KB). Monotone counter, no reset.
// Same pattern ROCm's grid.sync() lowers to: s_barrier cumulativity extends
// lane0's agent-scope fence over the whole block's prior writes.
// ---------------------------------------------------------------------------
__device__ __forceinline__ void grid_barrier(unsigned* cnt, unsigned target) {
  __syncthreads();
  if (threadIdx.x == 0) {
    __threadfence();  // release: block's qkv stores visible at device scope
    __hip_atomic_fetch_add(cnt, 1u, __ATOMIC_RELEASE, __HIP_MEMORY_SCOPE_AGENT);
    while (__hip_atomic_load(cnt, __ATOMIC_ACQUIRE, __HIP_MEMORY_SCOPE_AGENT) < target) {
      __builtin_amdgcn_s_sleep(8);
    }
    __threadfence();  // acquire: invalidate stale lines before reading peers' qkv
  }
  __syncthreads();
}

// ---------------------------------------------------------------------------
// Persistent mega-kernel: all 6 layers + fc head.
// grid = 192 blocks x 256 thr; block owns rows [blockIdx*64, +64).
// Only cross-block dependency is attention reading neighbors' qkv:
// double-buffered qkv => exactly ONE grid barrier per layer (after qkv write).
// LDS = As 16K + Bs 32K + Cs 16K = 64 KB.
// ---------------------------------------------------------------------------
__global__ void __launch_bounds__(256) mega_kernel(
    float* __restrict__ x, float* __restrict__ qkv0, float* __restrict__ qkv1,
    const unsigned short* __restrict__ wbf,
    const float* __restrict__ g1, const float* __restrict__ b1,
    const float* __restrict__ g2, const float* __restrict__ b2,
    const int* __restrict__ tt, const float* __restrict__ table,
    const int* __restrict__ adj, const int* __restrict__ adjc,
    const float* __restrict__ fcw, const float* __restrict__ fcb,
    float* __restrict__ out, unsigned* barrier_cnt) {
  __shared__ unsigned short As[64 * 128];   // 16 KB
  __shared__ unsigned short Bs[128 * 128];  // 32 KB
  __shared__ unsigned short Cs[64 * 128];   // 16 KB
  const int row0 = blockIdx.x * 64;
  const int b = row0 / S_;                   // 64-row tile within one batch
  const int t = threadIdx.x, w = t >> 6, lane = t & 63, quad = lane >> 4, l16 = lane & 15;
  const int rowbase = w * 16;
  const int tbase = tt[b] * D_;

  for (int l = 0; l < L_; ++l) {
    const unsigned short* wl = wbf + (size_t)l * WLAYER;
    const float* g1l = g1 + l * D_;
    const float* b1l = b1 + l * D_;
    const float* g2l = g2 + l * D_;
    const float* b2l = b2 + l * D_;
    float* qkv = (l & 1) ? qkv1 : qkv0;

    // ---------------- phase A: LN1 -> As; qkv = As @ Wqkv ----------------
    {  // 4 threads per row; wave w covers rows [16w,16w+16) = its MFMA rows
      const int r = t >> 2, c0 = (t & 3) * 32;
      const float* xr = x + (size_t)(row0 + r) * D_ + c0;
      f32x4 xv[8], gv[8], bv[8];
#pragma unroll
      for (int i = 0; i < 8; ++i) {
        xv[i] = *(const f32x4*)(xr + 4 * i);
        gv[i] = *(const f32x4*)(g1l + c0 + 4 * i);
        bv[i] = *(const f32x4*)(b1l + c0 + 4 * i);
      }
      float s = 0.f;
#pragma unroll
      for (int i = 0; i < 8; ++i) s += xv[i][0] + xv[i][1] + xv[i][2] + xv[i][3];
      s += __shfl_xor(s, 1); s += __shfl_xor(s, 2);
      const float mu = s * (1.f / 128.f);
      float sq = 0.f;
#pragma unroll
      for (int i = 0; i < 8; ++i)
#pragma unroll
        for (int j = 0; j < 4; ++j) { float d = xv[i][j] - mu; sq += d * d; }
      sq += __shfl_xor(sq, 1); sq += __shfl_xor(sq, 2);
      const float rstd = rsqrtf(sq * (1.f / 128.f) + 1e-5f);
#pragma unroll
      for (int k = 0; k < 4; ++k) {
        u16x8 pk;
#pragma unroll
        for (int j = 0; j < 8; ++j) {
          int m = k * 8 + j;
          pk[j] = f2bf((xv[m >> 2][m & 3] - mu) * rstd * gv[m >> 2][m & 3] + bv[m >> 2][m & 3]);
        }
        int c = (c0 >> 3) + k;
        *(u16x8*)&As[r * 128 + ((c ^ (r & 15)) << 3)] = pk;
      }
    }
    for (int seg = 0; seg < 3; ++seg) {
      for (int i = t; i < 2048; i += 256) {  // Bs <- seg's 128x128 weight tile
        int rr = i >> 4, cc = i & 15;
        uint4 vb = *(const uint4*)&wl[(size_t)(seg * 128 + rr) * 128 + cc * 8];
        *(uint4*)&Bs[rr * 128 + ((cc ^ (rr & 15)) << 3)] = vb;
      }
      __syncthreads();  // Bs staged; also covers As writes on seg==0
      f32x4 acc[8];
#pragma unroll
      for (int j = 0; j < 8; ++j) acc[j] = f32x4{0.f, 0.f, 0.f, 0.f};
      mfma16(As, Bs, rowbase, quad, l16, acc);
#pragma unroll
      for (int ct = 0; ct < 8; ++ct)
#pragma unroll
        for (int i = 0; i < 4; ++i) {
          int row = row0 + rowbase + quad * 4 + i;
          int col = seg * 128 + ct * 16 + l16;
          qkv[(size_t)row * 384 + col] = acc[ct][i];
        }
      __syncthreads();  // before next seg overwrites Bs
    }

    // -------- grid barrier: all blocks' qkv visible --------
    grid_barrier(barrier_cnt, (unsigned)(NBLK * (l + 1)));

    // ---------------- phase B1: sparse attention -> As (A-layout) ----------
    for (int task = t; task < 512; task += 256) {  // 64 rows x 8 heads
      const int rL = task >> 3, h = task & 7;
      const int row = row0 + rL;
      const int s = row - b * S_;
      const int cnt = adjc[s];
      const float* qrow = qkv + (size_t)row * 384 + h * 16;
      f32x4 q4[4];
#pragma unroll
      for (int i = 0; i < 4; ++i) q4[i] = *(const f32x4*)(qrow + 4 * i);
      float m = -1e30f, lsum = 0.f;
      f32x4 o4[4];
#pragma unroll
      for (int i = 0; i < 4; ++i) o4[i] = f32x4{0.f, 0.f, 0.f, 0.f};
      for (int j = 0; j < cnt; ++j) {
        const int key = adj[s * MAXDEG + j];
        const float* kr = qkv + (size_t)(b * S_ + key) * 384 + 128 + h * 16;
        f32x4 k4[4], v4[4];
#pragma unroll
        for (int i = 0; i < 4; ++i) k4[i] = *(const f32x4*)(kr + 4 * i);
#pragma unroll
        for (int i = 0; i < 4; ++i) v4[i] = *(const f32x4*)(kr + 128 + 4 * i);
        float dot = 0.f;
#pragma unroll
        for (int i = 0; i < 4; ++i)
#pragma unroll
          for (int d = 0; d < 4; ++d) dot = fmaf(q4[i][d], k4[i][d], dot);
        dot *= 0.25f;  // 1/sqrt(HD)
        const float mn = fmaxf(m, dot);
        const float rescale = __expf(m - mn);   // 0 on first iter
        const float e = __expf(dot - mn);
        lsum = lsum * rescale + e;
#pragma unroll
        for (int i = 0; i < 4; ++i)
#pragma unroll
          for (int d = 0; d < 4; ++d) o4[i][d] = o4[i][d] * rescale + e * v4[i][d];
        m = mn;
      }
      const float inv = 1.f / lsum;
#pragma unroll
      for (int half = 0; half < 2; ++half) {
        u16x8 pk;
#pragma unroll
        for (int jj = 0; jj < 8; ++jj) {
          int idx = half * 8 + jj;
          pk[jj] = f2bf(o4[idx >> 2][idx & 3] * inv);
        }
        const int cchunk = h * 2 + half;
        *(u16x8*)&As[rL * 128 + ((cchunk ^ (rL & 15)) << 3)] = pk;
      }
    }
    // stage Bs <- Wo^T while attn results land
    for (int i = t; i < 2048; i += 256) {
      int rr = i >> 4, cc = i & 15;
      uint4 vb = *(const uint4*)&wl[(size_t)(WSEG_QKV + rr * 128 + cc * 8)];
      *(uint4*)&Bs[rr * 128 + ((cc ^ (rr & 15)) << 3)] = vb;
    }
    __syncthreads();

    // ---------------- phase B2: x' = x + o@Wo; LN2*te; FFN; residual -------
    f32x4 acc1[8];
#pragma unroll
    for (int j = 0; j < 8; ++j) acc1[j] = f32x4{0.f, 0.f, 0.f, 0.f};
    mfma16(As, Bs, rowbase, quad, l16, acc1);
    f32x4 xp[8];
#pragma unroll
    for (int ct = 0; ct < 8; ++ct)
#pragma unroll
      for (int i = 0; i < 4; ++i) {
        int row = row0 + rowbase + quad * 4 + i;
        int col = ct * 16 + l16;
        xp[ct][i] = x[(size_t)row * D_ + col] + acc1[ct][i];
      }
    float mu_[4], rs_[4];
#pragma unroll
    for (int i = 0; i < 4; ++i) {
      float s = 0.f;
#pragma unroll
      for (int ct = 0; ct < 8; ++ct) s += xp[ct][i];
      for (int off = 1; off < 16; off <<= 1) s += __shfl_xor(s, off);
      float mu = s * (1.f / 128.f);
      float sq = 0.f;
#pragma unroll
      for (int ct = 0; ct < 8; ++ct) { float d = xp[ct][i] - mu; sq += d * d; }
      for (int off = 1; off < 16; off <<= 1) sq += __shfl_xor(sq, off);
      mu_[i] = mu;
      rs_[i] = rsqrtf(sq * (1.f / 128.f) + 1e-5f);
    }
    __syncthreads();  // done reading As(o)/Bs(Wo)
    // h2 = (LN2(x')*g+b)*te -> bf16 -> As
#pragma unroll
    for (int ct = 0; ct < 8; ++ct)
#pragma unroll
      for (int i = 0; i < 4; ++i) {
        int rowL = rowbase + quad * 4 + i;
        int col = ct * 16 + l16;
        float h2 = (xp[ct][i] - mu_[i]) * rs_[i] * g2l[col] + b2l[col];
        h2 *= table[tbase + col];
        As[rowL * 128 + (((col >> 3) ^ (rowL & 15)) << 3) + (col & 7)] = f2bf(h2);
      }
    f32x4 acc2[8];
#pragma unroll
    for (int j = 0; j < 8; ++j) acc2[j] = f32x4{0.f, 0.f, 0.f, 0.f};
    const unsigned short* w1 = wl + WSEG_QKV + WSEG_O;
    const unsigned short* w2 = wl + WSEG_QKV + WSEG_O + WSEG_1;
    for (int c = 0; c < 4; ++c) {
      for (int i = t; i < 2048; i += 256) {  // Bs <- W1t rows [c*128, +128)
        int rr = i >> 4, cc = i & 15;
        uint4 vb = *(const uint4*)&w1[(size_t)(c * 128 + rr) * 128 + cc * 8];
        *(uint4*)&Bs[rr * 128 + ((cc ^ (rr & 15)) << 3)] = vb;
      }
      __syncthreads();
      f32x4 accF[8];
#pragma unroll
      for (int j = 0; j < 8; ++j) accF[j] = f32x4{0.f, 0.f, 0.f, 0.f};
      mfma16(As, Bs, rowbase, quad, l16, accF);
#pragma unroll
      for (int ct = 0; ct < 8; ++ct)
#pragma unroll
        for (int i = 0; i < 4; ++i) {
          int rowL = rowbase + quad * 4 + i;
          int col = ct * 16 + l16;
          Cs[rowL * 128 + (((col >> 3) ^ (rowL & 15)) << 3) + (col & 7)] =
              f2bf(fmaxf(accF[ct][i], 0.f));
        }
      __syncthreads();  // Bs(W1) reads + Cs writes drained
      for (int i = t; i < 2048; i += 256) {  // Bs <- W2t k-chunk c
        int rr = i >> 4, cc = i & 15;
        uint4 vb = *(const uint4*)&w2[(size_t)rr * 512 + c * 128 + cc * 8];
        *(uint4*)&Bs[rr * 128 + ((cc ^ (rr & 15)) << 3)] = vb;
      }
      __syncthreads();
      mfma16(Cs, Bs, rowbase, quad, l16, acc2);
      __syncthreads();  // before next c overwrites Bs
    }
    // epilogue
    if (l < L_ - 1) {
#pragma unroll
      for (int ct = 0; ct < 8; ++ct)
#pragma unroll
        for (int i = 0; i < 4; ++i) {
          int row = row0 + rowbase + quad * 4 + i;
          int col = ct * 16 + l16;
          x[(size_t)row * D_ + col] = xp[ct][i] + acc2[ct][i];
        }
      __syncthreads();  // x visible block-locally before next LN1 read
    } else {
      float pr[4] = {0.f, 0.f, 0.f, 0.f};
#pragma unroll
      for (int ct = 0; ct < 8; ++ct)
#pragma unroll
        for (int i = 0; i < 4; ++i)
          pr[i] += (xp[ct][i] + acc2[ct][i]) * fcw[ct * 16 + l16];
#pragma unroll
      for (int i = 0; i < 4; ++i) {
        float s = pr[i];
        for (int off = 1; off < 16; off <<= 1) s += __shfl_xor(s, off);
        if (l16 == 0) out[row0 + rowbase + quad * 4 + i] = s + fcb[0];
      }
    }
  }
}

// ---------------------------------------------------------------------------
extern "C" void kernel_launch(void* const* d_in, const int* in_sizes, int n_in,
                              void* d_out, int out_size, void* d_ws, size_t ws_size,
                              hipStream_t stream) {
  const float* r_t       = (const float*)d_in[0];
  const int*   t         = (const int*)d_in[1];
  const int*   pcm       = (const int*)d_in[2];
  // d_in[3] = mask: unused, adjacency derived from pcm (identical support)
  const float* src_embed = (const float*)d_in[4];
  const float* time_tab  = (const float*)d_in[5];
  const float* Wq = (const float*)d_in[6];
  const float* Wk = (const float*)d_in[7];
  const float* Wv = (const float*)d_in[8];
  const float* Wo = (const float*)d_in[9];
  const float* W1 = (const float*)d_in[10];
  const float* W2 = (const float*)d_in[11];
  const float* g1 = (const float*)d_in[12];
  const float* b1 = (const float*)d_in[13];
  const float* g2 = (const float*)d_in[14];
  const float* b2 = (const float*)d_in[15];
  const float* fc_w = (const float*)d_in[16];
  const float* fc_b = (const float*)d_in[17];
  float* out = (float*)d_out;

  char* ws = (char*)d_ws;
  size_t off = 0;
  auto alloc = [&](size_t bytes) -> void* {
    void* p = ws + off;
    off = (off + bytes + 255) & ~(size_t)255;
    return p;
  };
  float*          x    = (float*)alloc((size_t)ROWS * D_ * 4);
  float*          qkv0 = (float*)alloc((size_t)ROWS * 384 * 4);
  float*          qkv1 = (float*)alloc((size_t)ROWS * 384 * 4);
  int*            adj  = (int*)alloc((size_t)S_ * MAXDEG * 4);
  int*            adjc = (int*)alloc((size_t)S_ * 4);
  unsigned short* wbf  = (unsigned short*)alloc((size_t)L_ * WLAYER * 2);
  unsigned*       bcnt = (unsigned*)alloc(256);

  adj_kernel<<<S_, 64, 0, stream>>>(pcm, adj, adjc);
  wconv_kernel<<<(L_ * WLAYER + 255) / 256, 256, 0, stream>>>(Wq, Wk, Wv, Wo, W1, W2, wbf);
  xinit_kernel<<<ROWS, 128, 0, stream>>>(r_t, adj, adjc, src_embed, t, time_tab, x, bcnt);

  mega_kernel<<<NBLK, 256, 0, stream>>>(x, qkv0, qkv1, wbf, g1, b1, g2, b2,
                                        t, time_tab, adj, adjc, fc_w, fc_b, out, bcnt);
}

// Round 8
// 480.593 us; speedup vs baseline: 1.0962x; 1.0962x over previous
//
#include <hip/hip_runtime.h>
#include <cmath>
#include <cstdint>

// Problem constants (from reference)
constexpr int B_ = 8, N_ = 1024, M_ = 512, D_ = 128, S_ = 1536, L_ = 6, DFF_ = 512;
constexpr int ROWS = B_ * S_;    // 12288
constexpr int MAXDEG = 64;       // max attention row degree (actual ~4-20)
constexpr int RPB  = 48;         // rows per block (1536 % 48 == 0: block within one batch)
constexpr int NBLK = ROWS / RPB; // 256 persistent blocks = 256 CUs (all resident)

typedef __bf16 bf16x8 __attribute__((ext_vector_type(8)));
typedef float  f32x4  __attribute__((ext_vector_type(4)));
typedef unsigned short u16x8 __attribute__((ext_vector_type(8)));

__device__ inline unsigned short f2bf(float f) {  // RNE fp32 -> bf16
  unsigned u = __float_as_uint(f);
  u += 0x7fffu + ((u >> 16) & 1u);
  return (unsigned short)(u >> 16);
}
__device__ inline float bf2f(unsigned short u) {
  return __uint_as_float(((unsigned)u) << 16);
}

// ---------------------------------------------------------------------------
// Adjacency from pcm: allowed(s,k) = (s==k) | Tanner edge. One wave per row.
// exp(-1e9-max) underflows to 0 in fp32 => sparse attention over this list is
// bit-equivalent to the dense masked softmax.
// ---------------------------------------------------------------------------
__global__ void adj_kernel(const int* __restrict__ pcm, int* __restrict__ adj,
                           int* __restrict__ adjcnt) {
  int s = blockIdx.x;
  int lane = threadIdx.x;  // 0..63
  int count = 0;
  for (int base = 0; base < S_; base += 64) {
    int k = base + lane;
    bool allowed;
    if (k == s) allowed = true;
    else if (s < N_ && k >= N_) allowed = pcm[(k - N_) * N_ + s] != 0;
    else if (s >= N_ && k < N_) allowed = pcm[(s - N_) * N_ + k] != 0;
    else allowed = false;
    unsigned long long bal = __ballot(allowed);
    if (allowed) {
      int slot = count + __popcll(bal & ((1ull << lane) - 1ull));
      if (slot < MAXDEG) adj[s * MAXDEG + slot] = k;
    }
    count += __popcll(bal);
  }
  if (lane == 0) adjcnt[s] = count < MAXDEG ? count : MAXDEG;
}

// ---------------------------------------------------------------------------
// x init; also zeroes the grid-barrier counter (ws poisoned 0xAA per call).
// ---------------------------------------------------------------------------
__global__ void xinit_kernel(const float* __restrict__ r_t, const int* __restrict__ adj,
                             const int* __restrict__ adjcnt, const float* __restrict__ se,
                             const int* __restrict__ tt, const float* __restrict__ table,
                             float* __restrict__ x, unsigned* __restrict__ barrier_cnt) {
  int bs = blockIdx.x;
  int b = bs / S_, s = bs % S_;
  int d = threadIdx.x;
  if (bs == 0 && d == 0) *barrier_cnt = 0u;
  float node;
  if (s < N_) {
    node = fabsf(r_t[b * N_ + s]);
  } else {
    int cnt = adjcnt[s];
    float sum = 0.f;
    for (int j = 0; j < cnt; ++j) {
      int k = adj[s * MAXDEG + j];
      if (k < N_) {
        float r = r_t[b * N_ + k];
        sum += (r < 0.f) ? 1.f : (r > 0.f ? 0.f : 0.5f);  // bits = 0.5*(1-sign)
      }
    }
    node = fmodf(sum, 2.0f);
  }
  x[(size_t)bs * D_ + d] = table[tt[b] * D_ + d] * se[s * D_ + d] * node;
}

// ---------------------------------------------------------------------------
// Weight convert: fp32 [K][N] -> bf16 transposed [N][K], per layer packed as
//   [3*128][128] (q,k,v) | [128][128] (o) | [512][128] (w1) | [128][512] (w2)
// ---------------------------------------------------------------------------
constexpr int WSEG_QKV = 3 * D_ * D_;
constexpr int WSEG_O   = D_ * D_;
constexpr int WSEG_1   = D_ * DFF_;
constexpr int WSEG_2   = DFF_ * D_;
constexpr int WLAYER   = WSEG_QKV + WSEG_O + WSEG_1 + WSEG_2;  // 196608

__global__ void wconv_kernel(const float* __restrict__ Wq, const float* __restrict__ Wk,
                             const float* __restrict__ Wv, const float* __restrict__ Wo,
                             const float* __restrict__ W1, const float* __restrict__ W2,
                             unsigned short* __restrict__ out) {
  int idx = blockIdx.x * blockDim.x + threadIdx.x;
  if (idx >= L_ * WLAYER) return;
  int l = idx / WLAYER, r = idx % WLAYER;
  float v;
  if (r < WSEG_QKV) {
    int which = r / (D_ * D_), i = r % (D_ * D_);
    int n = i / D_, kk = i % D_;
    const float* W = which == 0 ? Wq : (which == 1 ? Wk : Wv);
    v = W[(size_t)l * D_ * D_ + kk * D_ + n];
  } else if (r < WSEG_QKV + WSEG_O) {
    int i = r - WSEG_QKV;
    int n = i / D_, kk = i % D_;
    v = Wo[(size_t)l * D_ * D_ + kk * D_ + n];
  } else if (r < WSEG_QKV + WSEG_O + WSEG_1) {
    int i = r - WSEG_QKV - WSEG_O;
    int n = i / D_, kk = i % D_;
    v = W1[(size_t)l * D_ * DFF_ + kk * DFF_ + n];
  } else {
    int i = r - WSEG_QKV - WSEG_O - WSEG_1;
    int n = i / DFF_, kk = i % DFF_;
    v = W2[(size_t)l * DFF_ * D_ + kk * D_ + n];
  }
  out[idx] = f2bf(v);
}

// ---------------------------------------------------------------------------
// MFMA helper: wave tile = 16 rows x 64 cols (4 tiles of 16x16), K=128 in 4
// steps of 32. LDS: 16B chunks XOR-swizzled [row*128 + ((c^(row&15))<<3)].
// ---------------------------------------------------------------------------
__device__ __forceinline__ void mfma4(const unsigned short* As, const unsigned short* Bs,
                                      int rowbase, int colbase, int quad, int l16,
                                      f32x4 (&acc)[4]) {
#pragma unroll
  for (int kk = 0; kk < 4; ++kk) {
    int cb = kk * 4 + quad;
    int row = rowbase + l16;
    bf16x8 a = __builtin_bit_cast(bf16x8, *(const uint4*)&As[row * 128 + ((cb ^ (row & 15)) << 3)]);
    bf16x8 bb[4];
#pragma unroll
    for (int ct = 0; ct < 4; ++ct) {
      int n = colbase + ct * 16 + l16;
      bb[ct] = __builtin_bit_cast(bf16x8, *(const uint4*)&Bs[n * 128 + ((cb ^ (n & 15)) << 3)]);
    }
#pragma unroll
    for (int ct = 0; ct < 4; ++ct)
      acc[ct] = __builtin_amdgcn_mfma_f32_16x16x32_bf16(a, bb[ct], acc[ct], 0, 0, 0);
  }
}

// ---------------------------------------------------------------------------
// Grid barrier (R6-proven): threadfence release + device-scope atomic + spin
// + threadfence acquire. All 256 blocks hardware-resident => no deadlock.
// ---------------------------------------------------------------------------
__device__ __forceinline__ void grid_barrier(unsigned* cnt, unsigned target) {
  __syncthreads();
  if (threadIdx.x == 0) {
    __threadfence();  // release: this block's kv stores visible device-wide
    __hip_atomic_fetch_add(cnt, 1u, __ATOMIC_RELEASE, __HIP_MEMORY_SCOPE_AGENT);
    while (__hip_atomic_load(cnt, __ATOMIC_ACQUIRE, __HIP_MEMORY_SCOPE_AGENT) < target) {
      __builtin_amdgcn_s_sleep(8);
    }
    __threadfence();  // acquire: invalidate stale lines before reading peers' kv
  }
  __syncthreads();
}

// ---------------------------------------------------------------------------
// Persistent mega-kernel: all 6 layers + fc head.
// grid = 256 blocks x 384 thr (6 waves); block owns 48 rows.
// x held ENTIRELY in registers (block-private). Q block-local in LDS (Cs).
// Only K/V (bf16) cross blocks -> one fenced barrier per layer, kv dbuffered.
// LDS: As 12K + Bs 32K + Cs 12K + red ~0.8K ~= 57 KB.
// ---------------------------------------------------------------------------
__global__ void __launch_bounds__(384) mega_kernel(
    const float* __restrict__ x0, unsigned short* __restrict__ kv0,
    unsigned short* __restrict__ kv1, const unsigned short* __restrict__ wbf,
    const float* __restrict__ g1, const float* __restrict__ b1,
    const float* __restrict__ g2, const float* __restrict__ b2,
    const int* __restrict__ tt, const float* __restrict__ table,
    const int* __restrict__ adj, const int* __restrict__ adjc,
    const float* __restrict__ fcw, const float* __restrict__ fcb,
    float* __restrict__ out, unsigned* barrier_cnt) {
  __shared__ unsigned short As[RPB * 128];   // 12 KB
  __shared__ unsigned short Bs[128 * 128];   // 32 KB
  __shared__ unsigned short Cs[RPB * 128];   // 12 KB (holds Q, then FFN hf)
  __shared__ float red1[2][RPB], red2[2][RPB];
  const int row0 = blockIdx.x * RPB;
  const int b = row0 / S_;
  const int bS = b * S_;
  const int t = threadIdx.x, w = t >> 6, lane = t & 63, quad = lane >> 4, l16 = lane & 15;
  const int wr = w >> 1, wc = w & 1;
  const int rowbase = wr * 16, colbase = wc * 64;
  const int tbase = tt[b] * D_;

  // persistent x in registers, MFMA C-layout: xreg[ct][i] = x[row, col]
  // row = row0 + rowbase + quad*4 + i, col = colbase + ct*16 + l16
  f32x4 xreg[4];
#pragma unroll
  for (int ct = 0; ct < 4; ++ct)
#pragma unroll
    for (int i = 0; i < 4; ++i) {
      int row = row0 + rowbase + quad * 4 + i;
      int col = colbase + ct * 16 + l16;
      xreg[ct][i] = x0[(size_t)row * D_ + col];
    }

  for (int l = 0; l < L_; ++l) {
    const unsigned short* wl = wbf + (size_t)l * WLAYER;
    const float* g1l = g1 + l * D_;
    const float* b1l = b1 + l * D_;
    const float* g2l = g2 + l * D_;
    const float* b2l = b2 + l * D_;
    unsigned short* kv = (l & 1) ? kv1 : kv0;

    // ---------------- LN1 on register x (C-layout) -> bf16 h in As ---------
    float mu1[4], rs1[4];
#pragma unroll
    for (int i = 0; i < 4; ++i) {
      float s = xreg[0][i] + xreg[1][i] + xreg[2][i] + xreg[3][i];
      for (int off = 1; off < 16; off <<= 1) s += __shfl_xor(s, off);
      if (l16 == 0) red1[wc][rowbase + quad * 4 + i] = s;
    }
    __syncthreads();
#pragma unroll
    for (int i = 0; i < 4; ++i) {
      int r = rowbase + quad * 4 + i;
      mu1[i] = (red1[0][r] + red1[1][r]) * (1.f / 128.f);
      float sq = 0.f;
#pragma unroll
      for (int ct = 0; ct < 4; ++ct) { float d = xreg[ct][i] - mu1[i]; sq += d * d; }
      for (int off = 1; off < 16; off <<= 1) sq += __shfl_xor(sq, off);
      if (l16 == 0) red2[wc][r] = sq;
    }
    __syncthreads();
#pragma unroll
    for (int i = 0; i < 4; ++i) {
      int r = rowbase + quad * 4 + i;
      rs1[i] = rsqrtf((red2[0][r] + red2[1][r]) * (1.f / 128.f) + 1e-5f);
    }
#pragma unroll
    for (int ct = 0; ct < 4; ++ct)
#pragma unroll
      for (int i = 0; i < 4; ++i) {
        int rowL = rowbase + quad * 4 + i;
        int col = colbase + ct * 16 + l16;
        float h = (xreg[ct][i] - mu1[i]) * rs1[i] * g1l[col] + b1l[col];
        As[rowL * 128 + (((col >> 3) ^ (rowL & 15)) << 3) + (col & 7)] = f2bf(h);
      }

    // ---------------- QKV GEMM: q -> Cs (LDS), k/v -> global kv (bf16) -----
    for (int seg = 0; seg < 3; ++seg) {
      for (int i = t; i < 2048; i += 384) {
        int rr = i >> 4, cc = i & 15;
        uint4 vb = *(const uint4*)&wl[(size_t)(seg * 128 + rr) * 128 + cc * 8];
        *(uint4*)&Bs[rr * 128 + ((cc ^ (rr & 15)) << 3)] = vb;
      }
      __syncthreads();  // Bs staged; covers As/Cs hazards too
      f32x4 acc[4];
#pragma unroll
      for (int j = 0; j < 4; ++j) acc[j] = f32x4{0.f, 0.f, 0.f, 0.f};
      mfma4(As, Bs, rowbase, colbase, quad, l16, acc);
      if (seg == 0) {
#pragma unroll
        for (int ct = 0; ct < 4; ++ct)
#pragma unroll
          for (int i = 0; i < 4; ++i) {
            int rowL = rowbase + quad * 4 + i;
            int col = colbase + ct * 16 + l16;
            Cs[rowL * 128 + (((col >> 3) ^ (rowL & 15)) << 3) + (col & 7)] = f2bf(acc[ct][i]);
          }
      } else {
#pragma unroll
        for (int ct = 0; ct < 4; ++ct)
#pragma unroll
          for (int i = 0; i < 4; ++i) {
            int row = row0 + rowbase + quad * 4 + i;
            int col = (seg - 1) * 128 + colbase + ct * 16 + l16;
            kv[(size_t)row * 256 + col] = f2bf(acc[ct][i]);
          }
      }
      __syncthreads();  // before next seg overwrites Bs
    }

    // -------- fenced grid barrier: all blocks' kv visible ------------------
    grid_barrier(barrier_cnt, (unsigned)(NBLK * (l + 1)));

    // stage Bs <- Wo^T (loads in flight under the attention gather)
    for (int i = t; i < 2048; i += 384) {
      int rr = i >> 4, cc = i & 15;
      uint4 vb = *(const uint4*)&wl[(size_t)(WSEG_QKV + rr * 128 + cc * 8)];
      *(uint4*)&Bs[rr * 128 + ((cc ^ (rr & 15)) << 3)] = vb;
    }

    // ---------------- attention: one task per thread (48 rows x 8 heads) ---
    {
      const int rL = t >> 3, h = t & 7;
      const int s = row0 + rL - bS;
      const int cnt = adjc[s];
      float q[16];
      {
        u16x8 qa = *(const u16x8*)&Cs[rL * 128 + (((2 * h) ^ (rL & 15)) << 3)];
        u16x8 qb = *(const u16x8*)&Cs[rL * 128 + (((2 * h + 1) ^ (rL & 15)) << 3)];
#pragma unroll
        for (int j = 0; j < 8; ++j) { q[j] = bf2f(qa[j]); q[8 + j] = bf2f(qb[j]); }
      }
      float m = -1e30f, lsum = 0.f;
      float o16[16];
#pragma unroll
      for (int j = 0; j < 16; ++j) o16[j] = 0.f;
      for (int jb = 0; jb < cnt; jb += 8) {
        int keys[8];
        *(int4*)&keys[0] = *(const int4*)&adj[s * MAXDEG + jb];
        *(int4*)&keys[4] = *(const int4*)&adj[s * MAXDEG + jb + 4];
        u16x8 K[8][2], V[8][2];
#pragma unroll
        for (int u = 0; u < 8; ++u) {
          int key = (jb + u < cnt) ? keys[u] : 0;  // clamp: adj tail is poison
          const unsigned short* kp = kv + (size_t)(bS + key) * 256 + h * 16;
          K[u][0] = *(const u16x8*)(kp);
          K[u][1] = *(const u16x8*)(kp + 8);
          V[u][0] = *(const u16x8*)(kp + 128);
          V[u][1] = *(const u16x8*)(kp + 136);
        }
#pragma unroll
        for (int u = 0; u < 8; ++u) {
          float dot = 0.f;
#pragma unroll
          for (int j = 0; j < 8; ++j) {
            dot = fmaf(q[j], bf2f(K[u][0][j]), dot);
            dot = fmaf(q[8 + j], bf2f(K[u][1][j]), dot);
          }
          dot *= 0.25f;  // 1/sqrt(HD)
          if (jb + u >= cnt) dot = -1e30f;  // masked pad -> e = 0
          const float mn = fmaxf(m, dot);
          const float rescale = __expf(m - mn);
          const float e = __expf(dot - mn);
          lsum = lsum * rescale + e;
#pragma unroll
          for (int j = 0; j < 8; ++j) {
            o16[j]     = o16[j]     * rescale + e * bf2f(V[u][0][j]);
            o16[8 + j] = o16[8 + j] * rescale + e * bf2f(V[u][1][j]);
          }
          m = mn;
        }
      }
      const float inv = 1.f / lsum;
      u16x8 pk0, pk1;
#pragma unroll
      for (int j = 0; j < 8; ++j) {
        pk0[j] = f2bf(o16[j] * inv);
        pk1[j] = f2bf(o16[8 + j] * inv);
      }
      *(u16x8*)&As[rL * 128 + (((2 * h) ^ (rL & 15)) << 3)] = pk0;
      *(u16x8*)&As[rL * 128 + (((2 * h + 1) ^ (rL & 15)) << 3)] = pk1;
    }
    __syncthreads();  // As(o) writes + Bs(Wo) staging complete

    // ---------------- x' = x + o@Wo; LN2*te; FFN; residual -----------------
    f32x4 acc1[4];
#pragma unroll
    for (int j = 0; j < 4; ++j) acc1[j] = f32x4{0.f, 0.f, 0.f, 0.f};
    mfma4(As, Bs, rowbase, colbase, quad, l16, acc1);
    f32x4 xp[4];
#pragma unroll
    for (int ct = 0; ct < 4; ++ct)
#pragma unroll
      for (int i = 0; i < 4; ++i) xp[ct][i] = xreg[ct][i] + acc1[ct][i];
    // LN2 (row spans the two wc waves -> combine via LDS)
#pragma unroll
    for (int i = 0; i < 4; ++i) {
      float s = xp[0][i] + xp[1][i] + xp[2][i] + xp[3][i];
      for (int off = 1; off < 16; off <<= 1) s += __shfl_xor(s, off);
      if (l16 == 0) red1[wc][rowbase + quad * 4 + i] = s;
    }
    __syncthreads();
    float mu_[4], rs_[4];
#pragma unroll
    for (int i = 0; i < 4; ++i) {
      int r = rowbase + quad * 4 + i;
      mu_[i] = (red1[0][r] + red1[1][r]) * (1.f / 128.f);
      float sq = 0.f;
#pragma unroll
      for (int ct = 0; ct < 4; ++ct) { float d = xp[ct][i] - mu_[i]; sq += d * d; }
      for (int off = 1; off < 16; off <<= 1) sq += __shfl_xor(sq, off);
      if (l16 == 0) red2[wc][r] = sq;
    }
    __syncthreads();
#pragma unroll
    for (int i = 0; i < 4; ++i) {
      int r = rowbase + quad * 4 + i;
      rs_[i] = rsqrtf((red2[0][r] + red2[1][r]) * (1.f / 128.f) + 1e-5f);
    }
    // h2 = (LN2(x')*g+b)*te -> bf16 -> As
#pragma unroll
    for (int ct = 0; ct < 4; ++ct)
#pragma unroll
      for (int i = 0; i < 4; ++i) {
        int rowL = rowbase + quad * 4 + i;
        int col = colbase + ct * 16 + l16;
        float h2 = (xp[ct][i] - mu_[i]) * rs_[i] * g2l[col] + b2l[col];
        h2 *= table[tbase + col];
        As[rowL * 128 + (((col >> 3) ^ (rowL & 15)) << 3) + (col & 7)] = f2bf(h2);
      }
    f32x4 acc2[4];
#pragma unroll
    for (int j = 0; j < 4; ++j) acc2[j] = f32x4{0.f, 0.f, 0.f, 0.f};
    const unsigned short* w1 = wl + WSEG_QKV + WSEG_O;
    const unsigned short* w2 = wl + WSEG_QKV + WSEG_O + WSEG_1;
    for (int c = 0; c < 4; ++c) {
      for (int i = t; i < 2048; i += 384) {
        int rr = i >> 4, cc = i & 15;
        uint4 vb = *(const uint4*)&w1[(size_t)(c * 128 + rr) * 128 + cc * 8];
        *(uint4*)&Bs[rr * 128 + ((cc ^ (rr & 15)) << 3)] = vb;
      }
      __syncthreads();
      f32x4 accF[4];
#pragma unroll
      for (int j = 0; j < 4; ++j) accF[j] = f32x4{0.f, 0.f, 0.f, 0.f};
      mfma4(As, Bs, rowbase, colbase, quad, l16, accF);
#pragma unroll
      for (int ct = 0; ct < 4; ++ct)
#pragma unroll
        for (int i = 0; i < 4; ++i) {
          int rowL = rowbase + quad * 4 + i;
          int col = colbase + ct * 16 + l16;
          Cs[rowL * 128 + (((col >> 3) ^ (rowL & 15)) << 3) + (col & 7)] =
              f2bf(fmaxf(accF[ct][i], 0.f));
        }
      __syncthreads();  // Bs(W1) reads + Cs writes drained
      for (int i = t; i < 2048; i += 384) {
        int rr = i >> 4, cc = i & 15;
        uint4 vb = *(const uint4*)&w2[(size_t)rr * 512 + c * 128 + cc * 8];
        *(uint4*)&Bs[rr * 128 + ((cc ^ (rr & 15)) << 3)] = vb;
      }
      __syncthreads();
      mfma4(Cs, Bs, rowbase, colbase, quad, l16, acc2);
      __syncthreads();  // before next c overwrites Bs
    }
    // epilogue: x'' = x' + ffn (registers only)
    if (l < L_ - 1) {
#pragma unroll
      for (int ct = 0; ct < 4; ++ct)
#pragma unroll
        for (int i = 0; i < 4; ++i) xreg[ct][i] = xp[ct][i] + acc2[ct][i];
    } else {
      float pr[4] = {0.f, 0.f, 0.f, 0.f};
#pragma unroll
      for (int ct = 0; ct < 4; ++ct)
#pragma unroll
        for (int i = 0; i < 4; ++i)
          pr[i] += (xp[ct][i] + acc2[ct][i]) * fcw[colbase + ct * 16 + l16];
#pragma unroll
      for (int i = 0; i < 4; ++i) {
        float s = pr[i];
        for (int off = 1; off < 16; off <<= 1) s += __shfl_xor(s, off);
        if (l16 == 0) red1[wc][rowbase + quad * 4 + i] = s;
      }
      __syncthreads();
      if (wc == 0 && l16 == 0)
#pragma unroll
        for (int i = 0; i < 4; ++i) {
          int r = rowbase + quad * 4 + i;
          out[row0 + r] = red1[0][r] + red1[1][r] + fcb[0];
        }
    }
  }
}

// ---------------------------------------------------------------------------
extern "C" void kernel_launch(void* const* d_in, const int* in_sizes, int n_in,
                              void* d_out, int out_size, void* d_ws, size_t ws_size,
                              hipStream_t stream) {
  const float* r_t       = (const float*)d_in[0];
  const int*   t         = (const int*)d_in[1];
  const int*   pcm       = (const int*)d_in[2];
  // d_in[3] = mask: unused, adjacency derived from pcm (identical support)
  const float* src_embed = (const float*)d_in[4];
  const float* time_tab  = (const float*)d_in[5];
  const float* Wq = (const float*)d_in[6];
  const float* Wk = (const float*)d_in[7];
  const float* Wv = (const float*)d_in[8];
  const float* Wo = (const float*)d_in[9];
  const float* W1 = (const float*)d_in[10];
  const float* W2 = (const float*)d_in[11];
  const float* g1 = (const float*)d_in[12];
  const float* b1 = (const float*)d_in[13];
  const float* g2 = (const float*)d_in[14];
  const float* b2 = (const float*)d_in[15];
  const float* fc_w = (const float*)d_in[16];
  const float* fc_b = (const float*)d_in[17];
  float* out = (float*)d_out;

  char* ws = (char*)d_ws;
  size_t off = 0;
  auto alloc = [&](size_t bytes) -> void* {
    void* p = ws + off;
    off = (off + bytes + 255) & ~(size_t)255;
    return p;
  };
  float*          x    = (float*)alloc((size_t)ROWS * D_ * 4);
  unsigned short* kv0  = (unsigned short*)alloc((size_t)ROWS * 256 * 2);
  unsigned short* kv1  = (unsigned short*)alloc((size_t)ROWS * 256 * 2);
  int*            adj  = (int*)alloc((size_t)S_ * MAXDEG * 4);
  int*            adjc = (int*)alloc((size_t)S_ * 4);
  unsigned short* wbf  = (unsigned short*)alloc((size_t)L_ * WLAYER * 2);
  unsigned*       bcnt = (unsigned*)alloc(256);

  adj_kernel<<<S_, 64, 0, stream>>>(pcm, adj, adjc);
  wconv_kernel<<<(L_ * WLAYER + 255) / 256, 256, 0, stream>>>(Wq, Wk, Wv, Wo, W1, W2, wbf);
  xinit_kernel<<<ROWS, 128, 0, stream>>>(r_t, adj, adjc, src_embed, t, time_tab, x, bcnt);

  mega_kernel<<<NBLK, 384, 0, stream>>>(x, kv0, kv1, wbf, g1, b1, g2, b2,
                                        t, time_tab, adj, adjc, fc_w, fc_b, out, bcnt);
}